// Round 13
// baseline (499.782 us; speedup 1.0000x reference)
//
#include <hip/hip_runtime.h>
#include <math.h>
#include <stdio.h>

#define NN 131072
#define EE 2097152
#define GG 1024
#define NSLICE 256
#define SLICE_SHIFT 9             // 512 nodes per slice
#define SLICE_N 512
#define NCHUNK 256
#define CHUNK_E (EE / NCHUNK)     // 8192 edges per chunk
#define BCAP 96                   // bucket capacity; mean 32, 96 = mean+11sigma
#define PSPLIT 4                  // blocks per graph in proppool (8 regressed, m=R12)

typedef _Float16 half_t;
typedef _Float16 f16x2 __attribute__((ext_vector_type(2)));
typedef _Float16 f16x4 __attribute__((ext_vector_type(4)));
typedef float f32x4 __attribute__((ext_vector_type(4)));

// ---------------- atomic-free (global) graph build ----------------

__global__ __launch_bounds__(256) void k_part(const int* __restrict__ ei,
                                              const float* __restrict__ w,
                                              int* __restrict__ cnts,
                                              uint2* __restrict__ ebuf) {
    __shared__ int cur[NSLICE];
    int t = threadIdx.x, c = blockIdx.x;
    cur[t] = 0;
    __syncthreads();
    int e0 = c * CHUNK_E;
    for (int e = e0 + t; e < e0 + CHUNK_E; e += 256) {
        int d = ei[EE + e];
        int r = ei[e];
        float ww = w[e];
        int b = d >> SLICE_SHIFT;
        int pos = atomicAdd(&cur[b], 1);          // LDS atomic
        if (pos < BCAP) {
            uint2 p;
            p.x = ((unsigned)(d & (SLICE_N - 1)) << 17) | (unsigned)r;
            p.y = __float_as_uint(ww);
            ebuf[((size_t)c * NSLICE + b) * BCAP + pos] = p;
        }
    }
    __syncthreads();
    cnts[c * NSLICE + t] = min(cur[t], BCAP);
}

__global__ __launch_bounds__(256) void k_stot(const int* __restrict__ cnts,
                                              int* __restrict__ sbase,
                                              int* __restrict__ offs) {
    __shared__ int part[NSLICE];
    int t = threadIdx.x;
    int sum = 0;
    for (int c = 0; c < NCHUNK; ++c) sum += cnts[c * NSLICE + t];
    part[t] = sum;
    __syncthreads();
    for (int off = 1; off < NSLICE; off <<= 1) {
        int v = (t >= off) ? part[t - off] : 0;
        __syncthreads();
        part[t] += v;
        __syncthreads();
    }
    sbase[t] = (t == 0) ? 0 : part[t - 1];
    if (t == NSLICE - 1) offs[NN] = part[NSLICE - 1];
}

__global__ __launch_bounds__(512) void k_slice(const int* __restrict__ cnts,
                                               const uint2* __restrict__ ebuf,
                                               const int* __restrict__ sbase,
                                               const float* __restrict__ x,
                                               int* __restrict__ offs,
                                               float2* __restrict__ xd,
                                               uint2* __restrict__ pairs) {
    __shared__ int hcur[SLICE_N];
    __shared__ float dg[SLICE_N];
    __shared__ int part[512];
    int t = threadIdx.x;
    int s = blockIdx.x;
    int wv = t >> 6, lane = t & 63;   // 8 waves
    if (t < SLICE_N) { hcur[t] = 0; dg[t] = 1.0f; }
    __syncthreads();
    for (int c = wv; c < NCHUNK; c += 8) {
        int idx = c * NSLICE + s;
        int cnt = cnts[idx];
        const uint2* base = ebuf + (size_t)idx * BCAP;
        for (int i = lane; i < cnt; i += 64) {
            uint2 e = base[i];
            int dl = e.x >> 17;
            atomicAdd(&hcur[dl], 1);
            atomicAdd(&dg[dl], __uint_as_float(e.y));
        }
    }
    __syncthreads();
    int a = (t < SLICE_N) ? hcur[t] : 0;
    part[t] = a;
    __syncthreads();
    for (int off = 1; off < 512; off <<= 1) {
        int v = (t >= off) ? part[t - off] : 0;
        __syncthreads();
        part[t] += v;
        __syncthreads();
    }
    int ex = (t == 0) ? 0 : part[t - 1];
    int g0 = sbase[s] + ex;
    int nb = s * SLICE_N;
    if (t < SLICE_N) {
        hcur[t] = g0;
        offs[nb + t] = g0;
        float2 v0;
        v0.x = x[nb + t];
        v0.y = rsqrtf(dg[t]);
        xd[nb + t] = v0;
    }
    __syncthreads();
    for (int c = wv; c < NCHUNK; c += 8) {
        int idx = c * NSLICE + s;
        int cnt = cnts[idx];
        const uint2* base = ebuf + (size_t)idx * BCAP;
        for (int i = lane; i < cnt; i += 64) {
            uint2 e = base[i];
            int dl = e.x >> 17;
            int pos = atomicAdd(&hcur[dl], 1);    // LDS atomic
            uint2 p;
            p.x = e.x & 0x1FFFF;
            p.y = e.y;
            pairs[pos] = p;
        }
    }
}

// 16 lanes per node (4 nodes/wave): s = dn^2*x_n + sum (dn*w*dis_r)*x_r.
// Writes sd[n] = (s_n, dis_n). No pairs writeback (stays read-only, w raw).
__global__ __launch_bounds__(256) void k_s16(const float2* __restrict__ xd,
                                             const int* __restrict__ offs,
                                             const uint2* __restrict__ pairs,
                                             float2* __restrict__ sd) {
    int tid = blockIdx.x * 256 + threadIdx.x;
    int n = tid >> 4;
    int sl = tid & 15;
    float2 xdn = xd[n];
    float dn = xdn.y;
    int k0 = offs[n], k1 = offs[n + 1];
    float s = 0.f;
    for (int k = k0 + sl; k < k1; k += 16) {
        uint2 p = pairs[k];
        float2 xr = xd[p.x];                       // random 8B gather (L2-resident)
        s = fmaf(dn * __uint_as_float(p.y) * xr.y, xr.x, s);
    }
#pragma unroll
    for (int off = 8; off > 0; off >>= 1) s += __shfl_xor(s, off, 16);
    if (sl == 0) {
        float2 v;
        v.x = fmaf(dn * dn, xdn.x, s);
        v.y = dn;
        sd[n] = v;
    }
}

// prop0 rank-1: h1[src][j] = relu(s_src*W1[j]+b1[j]); norm inline (sd gathers).
__global__ __launch_bounds__(256) void k_prop0r(const float2* __restrict__ sd,
                                                const int* __restrict__ offs,
                                                const uint2* __restrict__ pairs,
                                                const float* __restrict__ W1,
                                                const float* __restrict__ b1,
                                                half_t* __restrict__ Bout) {
    int n = (blockIdx.x * 256 + threadIdx.x) >> 6;
    int lane = threadIdx.x & 63;
    float2 wv = ((const float2*)W1)[lane];
    float2 bv = ((const float2*)b1)[lane];
    float2 sdn = sd[n];
    float dn = sdn.y;
    float sn = dn * dn;
    float accx = sn * fmaxf(fmaf(sdn.x, wv.x, bv.x), 0.f);
    float accy = sn * fmaxf(fmaf(sdn.x, wv.y, bv.y), 0.f);
    float ax1 = 0.f, ay1 = 0.f, ax2 = 0.f, ay2 = 0.f, ax3 = 0.f, ay3 = 0.f;
    int k0 = offs[n], k1 = offs[n + 1];
    int k = k0;
    for (; k + 4 <= k1; k += 4) {
        uint2 p0 = pairs[k], p1 = pairs[k + 1], p2 = pairs[k + 2], p3 = pairs[k + 3];
        float2 v0 = sd[p0.x], v1 = sd[p1.x], v2 = sd[p2.x], v3 = sd[p3.x];
        float n0 = dn * __uint_as_float(p0.y) * v0.y;
        float n1 = dn * __uint_as_float(p1.y) * v1.y;
        float n2 = dn * __uint_as_float(p2.y) * v2.y;
        float n3 = dn * __uint_as_float(p3.y) * v3.y;
        accx = fmaf(n0, fmaxf(fmaf(v0.x, wv.x, bv.x), 0.f), accx);
        accy = fmaf(n0, fmaxf(fmaf(v0.x, wv.y, bv.y), 0.f), accy);
        ax1 = fmaf(n1, fmaxf(fmaf(v1.x, wv.x, bv.x), 0.f), ax1);
        ay1 = fmaf(n1, fmaxf(fmaf(v1.x, wv.y, bv.y), 0.f), ay1);
        ax2 = fmaf(n2, fmaxf(fmaf(v2.x, wv.x, bv.x), 0.f), ax2);
        ay2 = fmaf(n2, fmaxf(fmaf(v2.x, wv.y, bv.y), 0.f), ay2);
        ax3 = fmaf(n3, fmaxf(fmaf(v3.x, wv.x, bv.x), 0.f), ax3);
        ay3 = fmaf(n3, fmaxf(fmaf(v3.x, wv.y, bv.y), 0.f), ay3);
    }
    for (; k < k1; ++k) {
        uint2 p = pairs[k];
        float2 v = sd[p.x];
        float nm = dn * __uint_as_float(p.y) * v.y;
        accx = fmaf(nm, fmaxf(fmaf(v.x, wv.x, bv.x), 0.f), accx);
        accy = fmaf(nm, fmaxf(fmaf(v.x, wv.y, bv.y), 0.f), accy);
    }
    accx = (accx + ax1) + (ax2 + ax3);
    accy = (accy + ay1) + (ay2 + ay3);
    f16x2 o;
    o.x = (half_t)accx;
    o.y = (half_t)accy;
    ((f16x2*)Bout)[(size_t)n * 64 + lane] = o;
}

// ---- fused weight packing ----
__global__ __launch_bounds__(256) void k_wp(const float* __restrict__ W2,
                                            const float* __restrict__ W3,
                                            half_t* __restrict__ W2p,
                                            half_t* __restrict__ W3p) {
    int t = blockIdx.x * 256 + threadIdx.x;       // 65536
    if (t < 32768) {
        int slot = t & 3, lane = (t >> 2) & 63, ks = (t >> 8) & 7, nt = t >> 11;
        int col = nt * 16 + (lane & 15);
        int k = ks * 16 + (lane >> 4) * 4 + slot;
        W2p[t] = (half_t)W2[k * 256 + col];
    } else {
        int u = t - 32768;
        int slot = u & 3, lane = (u >> 2) & 63, ks = (u >> 8) & 15, nt = u >> 12;
        int col = nt * 16 + (lane & 15);
        int k = ks * 16 + (lane >> 4) * 4 + slot;
        W3p[u] = (half_t)W3[k * 128 + col];
    }
}

// Ah = (relu(Bh@W2+b2))@W3 -- MFMA f16, 2 row-tiles/wave (HW-verified layout)
__global__ __launch_bounds__(256) void k_gemm23(const half_t* __restrict__ Bh,
                                                const half_t* __restrict__ W2p,
                                                const float* __restrict__ b2,
                                                const half_t* __restrict__ W3p,
                                                half_t* __restrict__ Ah) {
    __shared__ __align__(16) char CtB[128 * 512];   // 64 KB, XOR-swizzled rows
    int n0 = blockIdx.x * 128;
    int t = threadIdx.x;
    int wv = t >> 6;
    int lane = t & 63;
    int lr = lane & 15;
    int lc = lane >> 4;

    f16x4 aA[8], aB[8];
    {
        const char* rowA = (const char*)(Bh + (size_t)(n0 + wv * 32 + lr) * 128) + lc * 8;
        const char* rowB = rowA + 16 * 128 * 2;
#pragma unroll
        for (int ks = 0; ks < 8; ++ks) {
            aA[ks] = *(const f16x4*)(rowA + ks * 32);
            aB[ks] = *(const f16x4*)(rowB + ks * 32);
        }
    }
    const f16x4* w2f = (const f16x4*)W2p;
    f32x4 accA[16], accB[16];
#pragma unroll
    for (int nt = 0; nt < 16; ++nt) {
        accA[nt] = (f32x4){0.f, 0.f, 0.f, 0.f};
        accB[nt] = (f32x4){0.f, 0.f, 0.f, 0.f};
    }
#pragma unroll
    for (int ks = 0; ks < 8; ++ks) {
#pragma unroll
        for (int h = 0; h < 2; ++h) {
            f16x4 b[8];
#pragma unroll
            for (int j = 0; j < 8; ++j) b[j] = w2f[((h * 8 + j) * 8 + ks) * 64 + lane];
#pragma unroll
            for (int j = 0; j < 8; ++j) {
                accA[h * 8 + j] = __builtin_amdgcn_mfma_f32_16x16x16f16(aA[ks], b[j], accA[h * 8 + j], 0, 0, 0);
                accB[h * 8 + j] = __builtin_amdgcn_mfma_f32_16x16x16f16(aB[ks], b[j], accB[h * 8 + j], 0, 0, 0);
            }
        }
    }
#pragma unroll
    for (int nt = 0; nt < 16; ++nt) {
        float bias = b2[nt * 16 + lr];
        int coff = (nt * 16 + lr) * 2;
#pragma unroll
        for (int r = 0; r < 4; ++r) {
            int rowA_ = wv * 32 + lc * 4 + r;
            int rowB_ = rowA_ + 16;
            float vA = fmaxf(accA[nt][r] + bias, 0.f);
            float vB = fmaxf(accB[nt][r] + bias, 0.f);
            *(half_t*)(CtB + rowA_ * 512 + (coff ^ ((rowA_ & 7) << 4))) = (half_t)vA;
            *(half_t*)(CtB + rowB_ * 512 + (coff ^ ((rowB_ & 7) << 4))) = (half_t)vB;
        }
    }
    __syncthreads();

    f16x4 a3A[16], a3B[16];
    {
        int rowA_ = wv * 32 + lr;
        int rowB_ = rowA_ + 16;
        const char* baseA = CtB + rowA_ * 512;
        const char* baseB = CtB + rowB_ * 512;
        int swA = (rowA_ & 7) << 4;
        int swB = (rowB_ & 7) << 4;
#pragma unroll
        for (int ks = 0; ks < 16; ++ks) {
            a3A[ks] = *(const f16x4*)(baseA + ((ks * 32 + lc * 8) ^ swA));
            a3B[ks] = *(const f16x4*)(baseB + ((ks * 32 + lc * 8) ^ swB));
        }
    }
    const f16x4* w3f = (const f16x4*)W3p;
    f32x4 acc3A[8], acc3B[8];
#pragma unroll
    for (int nt = 0; nt < 8; ++nt) {
        acc3A[nt] = (f32x4){0.f, 0.f, 0.f, 0.f};
        acc3B[nt] = (f32x4){0.f, 0.f, 0.f, 0.f};
    }
#pragma unroll
    for (int ks = 0; ks < 16; ++ks) {
        f16x4 cfr[8];
#pragma unroll
        for (int nt = 0; nt < 8; ++nt) cfr[nt] = w3f[(nt * 16 + ks) * 64 + lane];
#pragma unroll
        for (int nt = 0; nt < 8; ++nt) {
            acc3A[nt] = __builtin_amdgcn_mfma_f32_16x16x16f16(a3A[ks], cfr[nt], acc3A[nt], 0, 0, 0);
            acc3B[nt] = __builtin_amdgcn_mfma_f32_16x16x16f16(a3B[ks], cfr[nt], acc3B[nt], 0, 0, 0);
        }
    }
#pragma unroll
    for (int nt = 0; nt < 8; ++nt) {
#pragma unroll
        for (int r = 0; r < 4; ++r) {
            int rowA_ = n0 + wv * 32 + lc * 4 + r;
            Ah[(size_t)rowA_ * 128 + nt * 16 + lr] = (half_t)acc3A[nt][r];
            Ah[(size_t)(rowA_ + 16) * 128 + nt * 16 + lr] = (half_t)acc3B[nt][r];
        }
    }
}

// prop1 + pool, PSPLIT blocks per graph; g0 = graph offset (split dispatches).
// Norm inline: nrm = dn * w * sd[src].y (wave-uniform scalar loads).
__global__ __launch_bounds__(256) void k_proppool(const half_t* __restrict__ Ain,
                                                  const float2* __restrict__ sd,
                                                  const int* __restrict__ offs,
                                                  const uint2* __restrict__ pairs,
                                                  const float* __restrict__ b3,
                                                  const int* __restrict__ batch,
                                                  float* __restrict__ ppart,
                                                  int g0base) {
    __shared__ float psum[4 * 128];
    int b = blockIdx.x;
    int g = g0base + (b >> 2), q = b & 3;
    int t = threadIdx.x;
    int wv = t >> 6, lane = t & 63;
    for (int i = t; i < 512; i += 256) psum[i] = 0.f;
    __syncthreads();
    int lo = 0, hi = NN;
    while (lo < hi) { int mid = (lo + hi) >> 1; if (batch[mid] < g) lo = mid + 1; else hi = mid; }
    int s0 = lo;
    lo = s0; hi = NN;
    while (lo < hi) { int mid = (lo + hi) >> 1; if (batch[mid] < g + 1) lo = mid + 1; else hi = mid; }
    int s1 = lo;
    const f16x2* A2 = (const f16x2*)Ain;
    float2 bv = ((const float2*)b3)[lane];
    for (int n = s0 + q * 4 + wv; n < s1; n += 16) {
        float dn = sd[n].y;
        float sn = dn * dn;
        f16x2 av = A2[(size_t)n * 64 + lane];
        float ax0 = sn * (float)av.x, ay0 = sn * (float)av.y;
        float ax1 = 0.f, ay1 = 0.f, ax2 = 0.f, ay2 = 0.f, ax3 = 0.f, ay3 = 0.f;
        int k0 = offs[n], k1 = offs[n + 1];
        int k = k0;
        for (; k + 4 <= k1; k += 4) {
            uint2 p0 = pairs[k], p1 = pairs[k + 1], p2 = pairs[k + 2], p3 = pairs[k + 3];
            float n0 = dn * __uint_as_float(p0.y) * sd[p0.x].y;
            float n1 = dn * __uint_as_float(p1.y) * sd[p1.x].y;
            float n2 = dn * __uint_as_float(p2.y) * sd[p2.x].y;
            float n3 = dn * __uint_as_float(p3.y) * sd[p3.x].y;
            f16x2 r0 = A2[(size_t)p0.x * 64 + lane];
            f16x2 r1 = A2[(size_t)p1.x * 64 + lane];
            f16x2 r2 = A2[(size_t)p2.x * 64 + lane];
            f16x2 r3 = A2[(size_t)p3.x * 64 + lane];
            ax0 = fmaf(n0, (float)r0.x, ax0);
            ay0 = fmaf(n0, (float)r0.y, ay0);
            ax1 = fmaf(n1, (float)r1.x, ax1);
            ay1 = fmaf(n1, (float)r1.y, ay1);
            ax2 = fmaf(n2, (float)r2.x, ax2);
            ay2 = fmaf(n2, (float)r2.y, ay2);
            ax3 = fmaf(n3, (float)r3.x, ax3);
            ay3 = fmaf(n3, (float)r3.y, ay3);
        }
        for (; k < k1; ++k) {
            uint2 p = pairs[k];
            float nm = dn * __uint_as_float(p.y) * sd[p.x].y;
            f16x2 rv = A2[(size_t)p.x * 64 + lane];
            ax0 = fmaf(nm, (float)rv.x, ax0);
            ay0 = fmaf(nm, (float)rv.y, ay0);
        }
        float accx = (ax0 + ax1) + (ax2 + ax3);
        float accy = (ay0 + ay1) + (ay2 + ay3);
        accx = fmaxf(accx + bv.x, 0.f);
        accy = fmaxf(accy + bv.y, 0.f);
        psum[wv * 128 + 2 * lane]     += accx;
        psum[wv * 128 + 2 * lane + 1] += accy;
    }
    __syncthreads();
    if (t < 128) {
        int bb = (g - 0) * PSPLIT + q;   // global ppart slot (g is absolute)
        ppart[(size_t)bb * 128 + t] = psum[t] + psum[128 + t] + psum[256 + t] + psum[384 + t];
    }
}

// reduce PSPLIT partials + mean + MLP head, fused
__global__ __launch_bounds__(128) void k_mlp(const float* __restrict__ ppart,
                                             const int* __restrict__ batch,
                                             const float* __restrict__ Wf1,
                                             const float* __restrict__ bf1,
                                             const float* __restrict__ Wf2,
                                             const float* __restrict__ bf2,
                                             float* __restrict__ out) {
    __shared__ float p[128];
    __shared__ float z[32];
    int g = blockIdx.x;
    int t = threadIdx.x;
    int lo = 0, hi = NN;
    while (lo < hi) { int mid = (lo + hi) >> 1; if (batch[mid] < g) lo = mid + 1; else hi = mid; }
    int s0 = lo;
    lo = s0; hi = NN;
    while (lo < hi) { int mid = (lo + hi) >> 1; if (batch[mid] < g + 1) lo = mid + 1; else hi = mid; }
    int s1 = lo;
    float sum = 0.f;
#pragma unroll
    for (int q = 0; q < PSPLIT; ++q) sum += ppart[(size_t)(g * PSPLIT + q) * 128 + t];
    float c = (float)(s1 - s0);
    if (c < 1.f) c = 1.f;
    p[t] = sum / c;
    __syncthreads();
    if (t < 32) {
        float a = bf1[t];
        for (int k = 0; k < 128; ++k) a = fmaf(p[k], Wf1[k * 32 + t], a);
        z[t] = fmaxf(a, 0.f);
    }
    __syncthreads();
    if (t < 2) {
        float a = bf2[t];
        for (int j = 0; j < 32; ++j) a = fmaf(z[j], Wf2[j * 2 + t], a);
        out[g * 2 + t] = a;
    }
}

extern "C" void kernel_launch(void* const* d_in, const int* in_sizes, int n_in,
                              void* d_out, int out_size, void* d_ws, size_t ws_size,
                              hipStream_t stream) {
    const float* x   = (const float*)d_in[0];
    const int*   ei  = (const int*)d_in[1];
    const float* w   = (const float*)d_in[2];
    const int*   bat = (const int*)d_in[3];
    const float* W1  = (const float*)d_in[4];
    const float* b1  = (const float*)d_in[5];
    const float* W2  = (const float*)d_in[6];
    const float* b2  = (const float*)d_in[7];
    const float* W3  = (const float*)d_in[8];
    const float* b3  = (const float*)d_in[9];
    const float* Wf1 = (const float*)d_in[10];
    const float* bf1 = (const float*)d_in[11];
    const float* Wf2 = (const float*)d_in[12];
    const float* bf2 = (const float*)d_in[13];
    float* out = (float*)d_out;

    char* ws = (char*)d_ws;
    size_t o = 0;
    auto alloc = [&](size_t bytes) {
        void* p = ws + o;
        o += (bytes + 255) & ~(size_t)255;
        return p;
    };
    int*    offs   = (int*)alloc((size_t)(NN + 1) * 4);
    int*    sbase  = (int*)alloc((size_t)NSLICE * 4);
    int*    cnts   = (int*)alloc((size_t)NCHUNK * NSLICE * 4);           // 256 KB
    uint2*  ebuf   = (uint2*)alloc((size_t)NCHUNK * NSLICE * BCAP * 8);  // 48 MB
    float2* xd     = (float2*)alloc((size_t)NN * 8);                     // 1 MB
    float2* sd     = (float2*)alloc((size_t)NN * 8);                     // 1 MB
    uint2*  pairs  = (uint2*)alloc((size_t)EE * 8);                      // 16 MB
    half_t* Ah     = (half_t*)alloc((size_t)NN * 128 * 2);               // 32 MB
    half_t* Bh     = (half_t*)alloc((size_t)NN * 128 * 2);               // 32 MB
    half_t* W2p    = (half_t*)alloc((size_t)256 * 128 * 2);
    half_t* W3p    = (half_t*)alloc((size_t)128 * 256 * 2);
    float*  ppart  = (float*)alloc((size_t)GG * PSPLIT * 128 * 4);       // 2 MB

    if (o > ws_size) {
        fprintf(stderr, "[kernel_launch] ws_size=%zu < needed=%zu — aborting launch\n",
                ws_size, o);
        return;
    }

    k_part<<<NCHUNK, 256, 0, stream>>>(ei, w, cnts, ebuf);
    k_stot<<<1, 256, 0, stream>>>(cnts, sbase, offs);
    k_slice<<<NSLICE, 512, 0, stream>>>(cnts, ebuf, sbase, x, offs, xd, pairs);
    k_wp<<<256, 256, 0, stream>>>(W2, W3, W2p, W3p);
    k_s16<<<NN / 16, 256, 0, stream>>>(xd, offs, pairs, sd);
    k_prop0r<<<NN / 4, 256, 0, stream>>>(sd, offs, pairs, W1, b1, Bh);
    k_gemm23<<<NN / 128, 256, 0, stream>>>(Bh, W2p, b2, W3p, Ah);
    k_proppool<<<(GG / 2) * PSPLIT, 256, 0, stream>>>(Ah, sd, offs, pairs, b3, bat, ppart, 0);
    k_proppool<<<(GG / 2) * PSPLIT, 256, 0, stream>>>(Ah, sd, offs, pairs, b3, bat, ppart, GG / 2);
    k_mlp<<<GG, 128, 0, stream>>>(ppart, bat, Wf1, bf1, Wf2, bf2, out);
}

// Round 14
// 398.888 us; speedup vs baseline: 1.2529x; 1.2529x over previous
//
#include <hip/hip_runtime.h>
#include <math.h>
#include <stdio.h>

#define NN 131072
#define EE 2097152
#define GG 1024
#define NSLICE 256
#define SLICE_SHIFT 9             // 512 nodes per slice
#define SLICE_N 512
#define NCHUNK 256
#define CHUNK_E (EE / NCHUNK)     // 8192 edges per chunk
#define BCAP 96                   // bucket capacity; mean 32, 96 = mean+11sigma
#define PSPLIT 4                  // blocks per graph in proppool (8 regressed, R12)

typedef _Float16 half_t;
typedef _Float16 f16x2 __attribute__((ext_vector_type(2)));
typedef _Float16 f16x4 __attribute__((ext_vector_type(4)));
typedef float f32x4 __attribute__((ext_vector_type(4)));

// ---------------- atomic-free (global) graph build ----------------

__global__ __launch_bounds__(256) void k_part(const int* __restrict__ ei,
                                              const float* __restrict__ w,
                                              int* __restrict__ cnts,
                                              uint2* __restrict__ ebuf) {
    __shared__ int cur[NSLICE];
    int t = threadIdx.x, c = blockIdx.x;
    cur[t] = 0;
    __syncthreads();
    int e0 = c * CHUNK_E;
    for (int e = e0 + t; e < e0 + CHUNK_E; e += 256) {
        int d = ei[EE + e];
        int r = ei[e];
        float ww = w[e];
        int b = d >> SLICE_SHIFT;
        int pos = atomicAdd(&cur[b], 1);          // LDS atomic
        if (pos < BCAP) {
            uint2 p;
            p.x = ((unsigned)(d & (SLICE_N - 1)) << 17) | (unsigned)r;
            p.y = __float_as_uint(ww);
            ebuf[((size_t)c * NSLICE + b) * BCAP + pos] = p;
        }
    }
    __syncthreads();
    cnts[c * NSLICE + t] = min(cur[t], BCAP);
}

__global__ __launch_bounds__(256) void k_stot(const int* __restrict__ cnts,
                                              int* __restrict__ sbase,
                                              int* __restrict__ offs) {
    __shared__ int part[NSLICE];
    int t = threadIdx.x;
    int sum = 0;
    for (int c = 0; c < NCHUNK; ++c) sum += cnts[c * NSLICE + t];
    part[t] = sum;
    __syncthreads();
    for (int off = 1; off < NSLICE; off <<= 1) {
        int v = (t >= off) ? part[t - off] : 0;
        __syncthreads();
        part[t] += v;
        __syncthreads();
    }
    sbase[t] = (t == 0) ? 0 : part[t - 1];
    if (t == NSLICE - 1) offs[NN] = part[NSLICE - 1];
}

__global__ __launch_bounds__(512) void k_slice(const int* __restrict__ cnts,
                                               const uint2* __restrict__ ebuf,
                                               const int* __restrict__ sbase,
                                               const float* __restrict__ x,
                                               int* __restrict__ offs,
                                               float2* __restrict__ xd,
                                               uint2* __restrict__ pairs) {
    __shared__ int hcur[SLICE_N];
    __shared__ float dg[SLICE_N];
    __shared__ int part[512];
    int t = threadIdx.x;
    int s = blockIdx.x;
    int wv = t >> 6, lane = t & 63;   // 8 waves
    if (t < SLICE_N) { hcur[t] = 0; dg[t] = 1.0f; }
    __syncthreads();
    for (int c = wv; c < NCHUNK; c += 8) {
        int idx = c * NSLICE + s;
        int cnt = cnts[idx];
        const uint2* base = ebuf + (size_t)idx * BCAP;
        for (int i = lane; i < cnt; i += 64) {
            uint2 e = base[i];
            int dl = e.x >> 17;
            atomicAdd(&hcur[dl], 1);
            atomicAdd(&dg[dl], __uint_as_float(e.y));
        }
    }
    __syncthreads();
    int a = (t < SLICE_N) ? hcur[t] : 0;
    part[t] = a;
    __syncthreads();
    for (int off = 1; off < 512; off <<= 1) {
        int v = (t >= off) ? part[t - off] : 0;
        __syncthreads();
        part[t] += v;
        __syncthreads();
    }
    int ex = (t == 0) ? 0 : part[t - 1];
    int g0 = sbase[s] + ex;
    int nb = s * SLICE_N;
    if (t < SLICE_N) {
        hcur[t] = g0;
        offs[nb + t] = g0;
        float2 v0;
        v0.x = x[nb + t];
        v0.y = rsqrtf(dg[t]);
        xd[nb + t] = v0;
    }
    __syncthreads();
    for (int c = wv; c < NCHUNK; c += 8) {
        int idx = c * NSLICE + s;
        int cnt = cnts[idx];
        const uint2* base = ebuf + (size_t)idx * BCAP;
        for (int i = lane; i < cnt; i += 64) {
            uint2 e = base[i];
            int dl = e.x >> 17;
            int pos = atomicAdd(&hcur[dl], 1);    // LDS atomic
            uint2 p;
            p.x = e.x & 0x1FFFF;
            p.y = e.y;
            pairs[pos] = p;
        }
    }
}

// 16 lanes per node: compute norms (writeback pairs.y), reduce s -> sarr[n].
__global__ __launch_bounds__(256) void k_s16(const float2* __restrict__ xd,
                                             const int* __restrict__ offs,
                                             uint2* __restrict__ pairs,
                                             float* __restrict__ sarr) {
    int tid = blockIdx.x * 256 + threadIdx.x;
    int n = tid >> 4;
    int sl = tid & 15;
    float2 xdn = xd[n];
    float dn = xdn.y;
    int k0 = offs[n], k1 = offs[n + 1];
    float s = 0.f;
    for (int k = k0 + sl; k < k1; k += 16) {
        uint2 p = pairs[k];
        float2 xr = xd[p.x];                       // random 8B gather (L2-resident)
        float nrm = dn * __uint_as_float(p.y) * xr.y;
        pairs[k].y = __float_as_uint(nrm);         // writeback final norm
        s = fmaf(nrm, xr.x, s);
    }
#pragma unroll
    for (int off = 8; off > 0; off >>= 1) s += __shfl_xor(s, off, 16);
    if (sl == 0) sarr[n] = fmaf(dn * dn, xdn.x, s);
}

// prop0 rank-1, two-phase: wave owns 4 nodes.
// Phase A: 16 lanes/node, coalesced pairs + 4B sarr gathers -> wave-private LDS.
// Phase B: all-lane VALU reconstruction relu(s*W1+b1) from LDS broadcasts.
// No __syncthreads (wave-private LDS; lgkmcnt(0) orders within wave).
__global__ __launch_bounds__(256) void k_prop0r(const float* __restrict__ sarr,
                                                const float2* __restrict__ xd,
                                                const int* __restrict__ offs,
                                                const uint2* __restrict__ pairs,
                                                const float* __restrict__ W1,
                                                const float* __restrict__ b1,
                                                half_t* __restrict__ Bout) {
    __shared__ float2 buf[4][4][64];   // [wave][node][entry] = 8 KB
    int t = threadIdx.x;
    int wv = t >> 6, lane = t & 63;
    int sl = lane & 15, ng = lane >> 4;
    int nbase = (blockIdx.x * 4 + wv) * 4;
    int n = nbase + ng;
    int k0 = offs[n], k1 = offs[n + 1];
    int deg = k1 - k0;
    int md = deg;
    md = max(md, __shfl_xor(md, 16));
    md = max(md, __shfl_xor(md, 32));
    int rounds = (md + 63) >> 6;
    if (rounds < 1) rounds = 1;
    float2 wvp = ((const float2*)W1)[lane];
    float2 bvp = ((const float2*)b1)[lane];
    float sg = sarr[n];       // own s (uniform within group)
    float dgp = xd[n].y;      // own dis
    float accx[4] = {0.f, 0.f, 0.f, 0.f};
    float accy[4] = {0.f, 0.f, 0.f, 0.f};
    for (int rd = 0; rd < rounds; ++rd) {
        int kbase = k0 + rd * 64;
        int cnt = k1 - kbase;
        if (cnt > 64) cnt = 64;
#pragma unroll
        for (int i = 0; i < 4; ++i) {
            int idx = i * 16 + sl;
            if (idx < cnt) {
                uint2 p = pairs[kbase + idx];      // coalesced
                float2 v;
                v.x = __uint_as_float(p.y);        // nrm (precomputed)
                v.y = sarr[p.x];                   // 4B gather, L2-resident
                buf[wv][ng][idx] = v;
            }
        }
        asm volatile("s_waitcnt lgkmcnt(0)" ::: "memory");
#pragma unroll
        for (int nn = 0; nn < 4; ++nn) {
            int kk0 = __shfl(k0, nn * 16);
            int kk1 = __shfl(k1, nn * 16);
            int c = kk1 - (kk0 + rd * 64);
            if (c > 64) c = 64;
            for (int e = 0; e < c; ++e) {
                float2 v = buf[wv][nn][e];         // LDS broadcast
                accx[nn] = fmaf(v.x, fmaxf(fmaf(v.y, wvp.x, bvp.x), 0.f), accx[nn]);
                accy[nn] = fmaf(v.x, fmaxf(fmaf(v.y, wvp.y, bvp.y), 0.f), accy[nn]);
            }
        }
    }
#pragma unroll
    for (int nn = 0; nn < 4; ++nn) {
        float so = __shfl(sg, nn * 16);
        float dd = __shfl(dgp, nn * 16);
        float sn = dd * dd;
        float ax = fmaf(sn, fmaxf(fmaf(so, wvp.x, bvp.x), 0.f), accx[nn]);
        float ay = fmaf(sn, fmaxf(fmaf(so, wvp.y, bvp.y), 0.f), accy[nn]);
        f16x2 o;
        o.x = (half_t)ax;
        o.y = (half_t)ay;
        ((f16x2*)Bout)[(size_t)(nbase + nn) * 64 + lane] = o;
    }
}

// ---- fused weight packing ----
__global__ __launch_bounds__(256) void k_wp(const float* __restrict__ W2,
                                            const float* __restrict__ W3,
                                            half_t* __restrict__ W2p,
                                            half_t* __restrict__ W3p) {
    int t = blockIdx.x * 256 + threadIdx.x;       // 65536
    if (t < 32768) {
        int slot = t & 3, lane = (t >> 2) & 63, ks = (t >> 8) & 7, nt = t >> 11;
        int col = nt * 16 + (lane & 15);
        int k = ks * 16 + (lane >> 4) * 4 + slot;
        W2p[t] = (half_t)W2[k * 256 + col];
    } else {
        int u = t - 32768;
        int slot = u & 3, lane = (u >> 2) & 63, ks = (u >> 8) & 15, nt = u >> 12;
        int col = nt * 16 + (lane & 15);
        int k = ks * 16 + (lane >> 4) * 4 + slot;
        W3p[u] = (half_t)W3[k * 128 + col];
    }
}

// Ah = (relu(Bh@W2+b2))@W3 -- MFMA f16, 2 row-tiles/wave (HW-verified layout)
__global__ __launch_bounds__(256) void k_gemm23(const half_t* __restrict__ Bh,
                                                const half_t* __restrict__ W2p,
                                                const float* __restrict__ b2,
                                                const half_t* __restrict__ W3p,
                                                half_t* __restrict__ Ah) {
    __shared__ __align__(16) char CtB[128 * 512];   // 64 KB, XOR-swizzled rows
    int n0 = blockIdx.x * 128;
    int t = threadIdx.x;
    int wv = t >> 6;
    int lane = t & 63;
    int lr = lane & 15;
    int lc = lane >> 4;

    f16x4 aA[8], aB[8];
    {
        const char* rowA = (const char*)(Bh + (size_t)(n0 + wv * 32 + lr) * 128) + lc * 8;
        const char* rowB = rowA + 16 * 128 * 2;
#pragma unroll
        for (int ks = 0; ks < 8; ++ks) {
            aA[ks] = *(const f16x4*)(rowA + ks * 32);
            aB[ks] = *(const f16x4*)(rowB + ks * 32);
        }
    }
    const f16x4* w2f = (const f16x4*)W2p;
    f32x4 accA[16], accB[16];
#pragma unroll
    for (int nt = 0; nt < 16; ++nt) {
        accA[nt] = (f32x4){0.f, 0.f, 0.f, 0.f};
        accB[nt] = (f32x4){0.f, 0.f, 0.f, 0.f};
    }
#pragma unroll
    for (int ks = 0; ks < 8; ++ks) {
#pragma unroll
        for (int h = 0; h < 2; ++h) {
            f16x4 b[8];
#pragma unroll
            for (int j = 0; j < 8; ++j) b[j] = w2f[((h * 8 + j) * 8 + ks) * 64 + lane];
#pragma unroll
            for (int j = 0; j < 8; ++j) {
                accA[h * 8 + j] = __builtin_amdgcn_mfma_f32_16x16x16f16(aA[ks], b[j], accA[h * 8 + j], 0, 0, 0);
                accB[h * 8 + j] = __builtin_amdgcn_mfma_f32_16x16x16f16(aB[ks], b[j], accB[h * 8 + j], 0, 0, 0);
            }
        }
    }
#pragma unroll
    for (int nt = 0; nt < 16; ++nt) {
        float bias = b2[nt * 16 + lr];
        int coff = (nt * 16 + lr) * 2;
#pragma unroll
        for (int r = 0; r < 4; ++r) {
            int rowA_ = wv * 32 + lc * 4 + r;
            int rowB_ = rowA_ + 16;
            float vA = fmaxf(accA[nt][r] + bias, 0.f);
            float vB = fmaxf(accB[nt][r] + bias, 0.f);
            *(half_t*)(CtB + rowA_ * 512 + (coff ^ ((rowA_ & 7) << 4))) = (half_t)vA;
            *(half_t*)(CtB + rowB_ * 512 + (coff ^ ((rowB_ & 7) << 4))) = (half_t)vB;
        }
    }
    __syncthreads();

    f16x4 a3A[16], a3B[16];
    {
        int rowA_ = wv * 32 + lr;
        int rowB_ = rowA_ + 16;
        const char* baseA = CtB + rowA_ * 512;
        const char* baseB = CtB + rowB_ * 512;
        int swA = (rowA_ & 7) << 4;
        int swB = (rowB_ & 7) << 4;
#pragma unroll
        for (int ks = 0; ks < 16; ++ks) {
            a3A[ks] = *(const f16x4*)(baseA + ((ks * 32 + lc * 8) ^ swA));
            a3B[ks] = *(const f16x4*)(baseB + ((ks * 32 + lc * 8) ^ swB));
        }
    }
    const f16x4* w3f = (const f16x4*)W3p;
    f32x4 acc3A[8], acc3B[8];
#pragma unroll
    for (int nt = 0; nt < 8; ++nt) {
        acc3A[nt] = (f32x4){0.f, 0.f, 0.f, 0.f};
        acc3B[nt] = (f32x4){0.f, 0.f, 0.f, 0.f};
    }
#pragma unroll
    for (int ks = 0; ks < 16; ++ks) {
        f16x4 cfr[8];
#pragma unroll
        for (int nt = 0; nt < 8; ++nt) cfr[nt] = w3f[(nt * 16 + ks) * 64 + lane];
#pragma unroll
        for (int nt = 0; nt < 8; ++nt) {
            acc3A[nt] = __builtin_amdgcn_mfma_f32_16x16x16f16(a3A[ks], cfr[nt], acc3A[nt], 0, 0, 0);
            acc3B[nt] = __builtin_amdgcn_mfma_f32_16x16x16f16(a3B[ks], cfr[nt], acc3B[nt], 0, 0, 0);
        }
    }
#pragma unroll
    for (int nt = 0; nt < 8; ++nt) {
#pragma unroll
        for (int r = 0; r < 4; ++r) {
            int rowA_ = n0 + wv * 32 + lc * 4 + r;
            Ah[(size_t)rowA_ * 128 + nt * 16 + lr] = (half_t)acc3A[nt][r];
            Ah[(size_t)(rowA_ + 16) * 128 + nt * 16 + lr] = (half_t)acc3B[nt][r];
        }
    }
}

// prop1 + pool, PSPLIT blocks per graph, precomputed norms (R11 form, 99.5us)
__global__ __launch_bounds__(256) void k_proppool(const half_t* __restrict__ Ain,
                                                  const float2* __restrict__ xd,
                                                  const int* __restrict__ offs,
                                                  const uint2* __restrict__ pairs,
                                                  const float* __restrict__ b3,
                                                  const int* __restrict__ batch,
                                                  float* __restrict__ ppart) {
    __shared__ float psum[4 * 128];
    int b = blockIdx.x;
    int g = b >> 2, q = b & 3;
    int t = threadIdx.x;
    int wv = t >> 6, lane = t & 63;
    for (int i = t; i < 512; i += 256) psum[i] = 0.f;
    __syncthreads();
    int lo = 0, hi = NN;
    while (lo < hi) { int mid = (lo + hi) >> 1; if (batch[mid] < g) lo = mid + 1; else hi = mid; }
    int s0 = lo;
    lo = s0; hi = NN;
    while (lo < hi) { int mid = (lo + hi) >> 1; if (batch[mid] < g + 1) lo = mid + 1; else hi = mid; }
    int s1 = lo;
    const f16x2* A2 = (const f16x2*)Ain;
    float2 bv = ((const float2*)b3)[lane];
    for (int n = s0 + q * 4 + wv; n < s1; n += 16) {
        float dn = xd[n].y;
        float sn = dn * dn;
        f16x2 av = A2[(size_t)n * 64 + lane];
        float ax0 = sn * (float)av.x, ay0 = sn * (float)av.y;
        float ax1 = 0.f, ay1 = 0.f, ax2 = 0.f, ay2 = 0.f, ax3 = 0.f, ay3 = 0.f;
        int k0 = offs[n], k1 = offs[n + 1];
        int k = k0;
        for (; k + 8 <= k1; k += 8) {
            uint2 p0 = pairs[k],     p1 = pairs[k + 1], p2 = pairs[k + 2], p3 = pairs[k + 3];
            uint2 p4 = pairs[k + 4], p5 = pairs[k + 5], p6 = pairs[k + 6], p7 = pairs[k + 7];
            f16x2 r0 = A2[(size_t)p0.x * 64 + lane];
            f16x2 r1 = A2[(size_t)p1.x * 64 + lane];
            f16x2 r2 = A2[(size_t)p2.x * 64 + lane];
            f16x2 r3 = A2[(size_t)p3.x * 64 + lane];
            f16x2 r4 = A2[(size_t)p4.x * 64 + lane];
            f16x2 r5 = A2[(size_t)p5.x * 64 + lane];
            f16x2 r6 = A2[(size_t)p6.x * 64 + lane];
            f16x2 r7 = A2[(size_t)p7.x * 64 + lane];
            ax0 = fmaf(__uint_as_float(p0.y), (float)r0.x, ax0);
            ay0 = fmaf(__uint_as_float(p0.y), (float)r0.y, ay0);
            ax1 = fmaf(__uint_as_float(p1.y), (float)r1.x, ax1);
            ay1 = fmaf(__uint_as_float(p1.y), (float)r1.y, ay1);
            ax2 = fmaf(__uint_as_float(p2.y), (float)r2.x, ax2);
            ay2 = fmaf(__uint_as_float(p2.y), (float)r2.y, ay2);
            ax3 = fmaf(__uint_as_float(p3.y), (float)r3.x, ax3);
            ay3 = fmaf(__uint_as_float(p3.y), (float)r3.y, ay3);
            ax0 = fmaf(__uint_as_float(p4.y), (float)r4.x, ax0);
            ay0 = fmaf(__uint_as_float(p4.y), (float)r4.y, ay0);
            ax1 = fmaf(__uint_as_float(p5.y), (float)r5.x, ax1);
            ay1 = fmaf(__uint_as_float(p5.y), (float)r5.y, ay1);
            ax2 = fmaf(__uint_as_float(p6.y), (float)r6.x, ax2);
            ay2 = fmaf(__uint_as_float(p6.y), (float)r6.y, ay2);
            ax3 = fmaf(__uint_as_float(p7.y), (float)r7.x, ax3);
            ay3 = fmaf(__uint_as_float(p7.y), (float)r7.y, ay3);
        }
        for (; k + 4 <= k1; k += 4) {
            uint2 p0 = pairs[k], p1 = pairs[k + 1], p2 = pairs[k + 2], p3 = pairs[k + 3];
            f16x2 r0 = A2[(size_t)p0.x * 64 + lane];
            f16x2 r1 = A2[(size_t)p1.x * 64 + lane];
            f16x2 r2 = A2[(size_t)p2.x * 64 + lane];
            f16x2 r3 = A2[(size_t)p3.x * 64 + lane];
            ax0 = fmaf(__uint_as_float(p0.y), (float)r0.x, ax0);
            ay0 = fmaf(__uint_as_float(p0.y), (float)r0.y, ay0);
            ax1 = fmaf(__uint_as_float(p1.y), (float)r1.x, ax1);
            ay1 = fmaf(__uint_as_float(p1.y), (float)r1.y, ay1);
            ax2 = fmaf(__uint_as_float(p2.y), (float)r2.x, ax2);
            ay2 = fmaf(__uint_as_float(p2.y), (float)r2.y, ay2);
            ax3 = fmaf(__uint_as_float(p3.y), (float)r3.x, ax3);
            ay3 = fmaf(__uint_as_float(p3.y), (float)r3.y, ay3);
        }
        for (; k < k1; ++k) {
            uint2 p = pairs[k];
            f16x2 rv = A2[(size_t)p.x * 64 + lane];
            ax0 = fmaf(__uint_as_float(p.y), (float)rv.x, ax0);
            ay0 = fmaf(__uint_as_float(p.y), (float)rv.y, ay0);
        }
        float accx = (ax0 + ax1) + (ax2 + ax3);
        float accy = (ay0 + ay1) + (ay2 + ay3);
        accx = fmaxf(accx + bv.x, 0.f);
        accy = fmaxf(accy + bv.y, 0.f);
        psum[wv * 128 + 2 * lane]     += accx;
        psum[wv * 128 + 2 * lane + 1] += accy;
    }
    __syncthreads();
    if (t < 128) {
        ppart[(size_t)b * 128 + t] = psum[t] + psum[128 + t] + psum[256 + t] + psum[384 + t];
    }
}

// reduce PSPLIT partials + mean + MLP head, fused
__global__ __launch_bounds__(128) void k_mlp(const float* __restrict__ ppart,
                                             const int* __restrict__ batch,
                                             const float* __restrict__ Wf1,
                                             const float* __restrict__ bf1,
                                             const float* __restrict__ Wf2,
                                             const float* __restrict__ bf2,
                                             float* __restrict__ out) {
    __shared__ float p[128];
    __shared__ float z[32];
    int g = blockIdx.x;
    int t = threadIdx.x;
    int lo = 0, hi = NN;
    while (lo < hi) { int mid = (lo + hi) >> 1; if (batch[mid] < g) lo = mid + 1; else hi = mid; }
    int s0 = lo;
    lo = s0; hi = NN;
    while (lo < hi) { int mid = (lo + hi) >> 1; if (batch[mid] < g + 1) lo = mid + 1; else hi = mid; }
    int s1 = lo;
    float sum = 0.f;
#pragma unroll
    for (int q = 0; q < PSPLIT; ++q) sum += ppart[(size_t)(g * PSPLIT + q) * 128 + t];
    float c = (float)(s1 - s0);
    if (c < 1.f) c = 1.f;
    p[t] = sum / c;
    __syncthreads();
    if (t < 32) {
        float a = bf1[t];
        for (int k = 0; k < 128; ++k) a = fmaf(p[k], Wf1[k * 32 + t], a);
        z[t] = fmaxf(a, 0.f);
    }
    __syncthreads();
    if (t < 2) {
        float a = bf2[t];
        for (int j = 0; j < 32; ++j) a = fmaf(z[j], Wf2[j * 2 + t], a);
        out[g * 2 + t] = a;
    }
}

extern "C" void kernel_launch(void* const* d_in, const int* in_sizes, int n_in,
                              void* d_out, int out_size, void* d_ws, size_t ws_size,
                              hipStream_t stream) {
    const float* x   = (const float*)d_in[0];
    const int*   ei  = (const int*)d_in[1];
    const float* w   = (const float*)d_in[2];
    const int*   bat = (const int*)d_in[3];
    const float* W1  = (const float*)d_in[4];
    const float* b1  = (const float*)d_in[5];
    const float* W2  = (const float*)d_in[6];
    const float* b2  = (const float*)d_in[7];
    const float* W3  = (const float*)d_in[8];
    const float* b3  = (const float*)d_in[9];
    const float* Wf1 = (const float*)d_in[10];
    const float* bf1 = (const float*)d_in[11];
    const float* Wf2 = (const float*)d_in[12];
    const float* bf2 = (const float*)d_in[13];
    float* out = (float*)d_out;

    char* ws = (char*)d_ws;
    size_t o = 0;
    auto alloc = [&](size_t bytes) {
        void* p = ws + o;
        o += (bytes + 255) & ~(size_t)255;
        return p;
    };
    int*    offs   = (int*)alloc((size_t)(NN + 1) * 4);
    int*    sbase  = (int*)alloc((size_t)NSLICE * 4);
    int*    cnts   = (int*)alloc((size_t)NCHUNK * NSLICE * 4);           // 256 KB
    uint2*  ebuf   = (uint2*)alloc((size_t)NCHUNK * NSLICE * BCAP * 8);  // 48 MB
    float2* xd     = (float2*)alloc((size_t)NN * 8);                     // 1 MB
    float*  sarr   = (float*)alloc((size_t)NN * 4);                      // 512 KB
    uint2*  pairs  = (uint2*)alloc((size_t)EE * 8);                      // 16 MB
    half_t* Ah     = (half_t*)alloc((size_t)NN * 128 * 2);               // 32 MB
    half_t* Bh     = (half_t*)alloc((size_t)NN * 128 * 2);               // 32 MB
    half_t* W2p    = (half_t*)alloc((size_t)256 * 128 * 2);
    half_t* W3p    = (half_t*)alloc((size_t)128 * 256 * 2);
    float*  ppart  = (float*)alloc((size_t)GG * PSPLIT * 128 * 4);       // 2 MB

    if (o > ws_size) {
        fprintf(stderr, "[kernel_launch] ws_size=%zu < needed=%zu — aborting launch\n",
                ws_size, o);
        return;
    }

    k_part<<<NCHUNK, 256, 0, stream>>>(ei, w, cnts, ebuf);
    k_stot<<<1, 256, 0, stream>>>(cnts, sbase, offs);
    k_slice<<<NSLICE, 512, 0, stream>>>(cnts, ebuf, sbase, x, offs, xd, pairs);
    k_wp<<<256, 256, 0, stream>>>(W2, W3, W2p, W3p);
    k_s16<<<NN / 16, 256, 0, stream>>>(xd, offs, pairs, sarr);
    k_prop0r<<<NN / 16, 256, 0, stream>>>(sarr, xd, offs, pairs, W1, b1, Bh);
    k_gemm23<<<NN / 128, 256, 0, stream>>>(Bh, W2p, b2, W3p, Ah);
    k_proppool<<<GG * PSPLIT, 256, 0, stream>>>(Ah, xd, offs, pairs, b3, bat, ppart);
    k_mlp<<<GG, 128, 0, stream>>>(ppart, bat, Wf1, bf1, Wf2, bf2, out);
}